// Round 19
// baseline (166.799 us; speedup 1.0000x reference)
//
#include <hip/hip_runtime.h>

#define NS 10000
#define DD 64
#define HH 128
#define EE 50000
#define SLOPE 0.01f
#define BPAD 8448      // B^T row length in c (33 chunks x 256; 8192 w2 + 64 b2 + 192 zero)
#define LROW 264       // LDS row stride (shorts): 256 + 8 pad, 16B aligned
#define NCH 33

typedef __attribute__((ext_vector_type(8))) short short8;
typedef __attribute__((ext_vector_type(4))) short bf4;
typedef __attribute__((ext_vector_type(4))) float f32x4;

static __device__ __forceinline__ unsigned short f2bf(float f) {
  unsigned int u = __float_as_uint(f);
  u += 0x7fff + ((u >> 16) & 1);   // round-to-nearest-even
  return (unsigned short)(u >> 16);
}
static __device__ __forceinline__ float bf2f(unsigned short s) {
  return __uint_as_float((unsigned int)s << 16);
}
static __device__ __forceinline__ unsigned cvtpk(float lo, float hi) {
  unsigned r;
  asm("v_cvt_pk_bf16_f32 %0, %1, %2" : "=v"(r) : "v"(lo), "v"(hi));
  return r;
}

__device__ __forceinline__ float wave_sum64(float v) {
  #pragma unroll
  for (int m = 32; m >= 1; m >>= 1) v += __shfl_xor(v, m, 64);
  return v;
}

// k_prep: [0,128): w2 64x64 LDS transpose -> w2e rows (stride BPAD).
//         [128]: b2 rows + zero pad of w2e.
//         [129, 129+2500): LN -> h/hbf, cntdst.
//         [2629, 2629+782): u-GEMM (inline ea cast + w1 LDS transpose) -> ubf.
// agg|cntdst zeroed by a prior memset (r13 race lesson).
#define TBLK 128
#define PBLK 2500
#define UB 782
__global__ __launch_bounds__(256) void k_prep(const float* __restrict__ x,
    const float* __restrict__ gamma, const float* __restrict__ beta,
    float* __restrict__ h, unsigned short* __restrict__ hbf,
    const float* __restrict__ ea, const float* __restrict__ w2,
    unsigned short* __restrict__ w2e, const float* __restrict__ w1,
    const float* __restrict__ b1, unsigned short* __restrict__ ubf,
    const float* __restrict__ b2, const int* __restrict__ ei,
    int* __restrict__ cntdst) {
  __shared__ __align__(16) unsigned char smem[18432];
  int t = threadIdx.x;
  int bid = blockIdx.x;
  if (bid < TBLK) {
    float (*tile)[65] = (float(*)[65])smem;   // 16640 B
    int k = bid;
    #pragma unroll
    for (int i = 0; i < 16; ++i) {
      int idx = t + i * 256;          // d*64+f
      tile[idx >> 6][idx & 63] = w2[k * (DD * DD) + idx];
    }
    __syncthreads();
    #pragma unroll
    for (int it = 0; it < 2; ++it) {
      int slot = t + it * 256;        // 0..511
      int f = slot >> 3, l8 = slot & 7;
      short8 o;
      #pragma unroll
      for (int j = 0; j < 8; ++j) o[j] = f2bf(tile[l8 * 8 + j][f]);
      *(short8*)(w2e + (size_t)f * BPAD + k * DD + l8 * 8) = o;
    }
    return;
  }
  if (bid == TBLK) {
    // b2 rows: w2e[f][8192+d] = b2[d*64+f]
    #pragma unroll
    for (int i = 0; i < 16; ++i) {
      int idx = t + i * 256;          // d*64+f
      int d = idx >> 6, f = idx & 63;
      w2e[(size_t)f * BPAD + 8192 + d] = f2bf(b2[idx]);
    }
    // zero pad: c in [8256, 8448)
    #pragma unroll
    for (int i = 0; i < 6; ++i) {
      int slot = t + i * 256;         // 0..1535
      int f = slot / 24, z8 = slot % 24;
      short8 z = {};
      *(short8*)(w2e + (size_t)f * BPAD + 8256 + z8 * 8) = z;
    }
    return;
  }
  if (bid < TBLK + 1 + PBLK) {
    int pbid = bid - TBLK - 1;
    int gid = pbid * 256 + t;
    if (gid < EE) atomicAdd(&cntdst[ei[EE + gid]], 1);
    int wid = t >> 6;
    int lane = t & 63;
    int row = pbid * 4 + wid;
    if (row >= NS) return;
    float v = x[row * DD + lane];
    float s = wave_sum64(v);
    float s2 = wave_sum64(v * v);
    float mu = s * (1.0f / 64.0f);
    float var = s2 * (1.0f / 64.0f) - mu * mu;
    float r = rsqrtf(var + 1e-5f);
    float hn = (v - mu) * r * gamma[lane] + beta[lane];
    float hv = hn >= 0.f ? hn : SLOPE * hn;
    h[row * DD + lane] = hv;
    hbf[row * DD + lane] = f2bf(hv);
    return;
  }
  // u-GEMM: 64 edge-rows per block, inline ea cast, w1 via LDS transpose.
  int ublk = bid - TBLK - 1 - PBLK;
  unsigned short (*W)[72] = (unsigned short(*)[72])smem;   // 128x72 shorts
  int w = t >> 6, lane = t & 63, lr = lane & 15, lg = lane >> 4;
  int r0 = ublk * 64 + w * 16;
  int ra = r0 + lr; if (ra >= EE) ra = EE - 1;
  const float* ep = ea + (size_t)ra * DD;
  float4 e0 = *(const float4*)(ep + lg * 8);
  float4 e1 = *(const float4*)(ep + lg * 8 + 4);
  float4 e2 = *(const float4*)(ep + 32 + lg * 8);
  float4 e3 = *(const float4*)(ep + 32 + lg * 8 + 4);
  #pragma unroll
  for (int i = 0; i < 32; ++i) {
    int idx = t + i * 256;            // idx = d*128 + hc
    int d = idx >> 7, hc = idx & 127;
    W[hc][d] = f2bf(w1[idx]);
  }
  __syncthreads();
  short8 a0, a1;
  a0[0] = f2bf(e0.x); a0[1] = f2bf(e0.y); a0[2] = f2bf(e0.z); a0[3] = f2bf(e0.w);
  a0[4] = f2bf(e1.x); a0[5] = f2bf(e1.y); a0[6] = f2bf(e1.z); a0[7] = f2bf(e1.w);
  a1[0] = f2bf(e2.x); a1[1] = f2bf(e2.y); a1[2] = f2bf(e2.z); a1[3] = f2bf(e2.w);
  a1[4] = f2bf(e3.x); a1[5] = f2bf(e3.y); a1[6] = f2bf(e3.z); a1[7] = f2bf(e3.w);
  short8 bb0[8], bb1[8];
  #pragma unroll
  for (int ni = 0; ni < 8; ++ni) {
    bb0[ni] = *(const short8*)(&W[ni * 16 + lr][lg * 8]);
    bb1[ni] = *(const short8*)(&W[ni * 16 + lr][32 + lg * 8]);
  }
  f32x4 acc[8] = {};
  #pragma unroll
  for (int ni = 0; ni < 8; ++ni) {
    acc[ni] = __builtin_amdgcn_mfma_f32_16x16x32_bf16(a0, bb0[ni], acc[ni], 0, 0, 0);
    acc[ni] = __builtin_amdgcn_mfma_f32_16x16x32_bf16(a1, bb1[ni], acc[ni], 0, 0, 0);
  }
  #pragma unroll
  for (int ni = 0; ni < 8; ++ni) {
    int col = ni * 16 + lr;
    float bb = b1[col];
    #pragma unroll
    for (int reg = 0; reg < 4; ++reg) {
      int gr = r0 + lg * 4 + reg;
      if (gr < EE) {
        float vv = acc[ni][reg] + bb;
        ubf[(size_t)gr * HH + col] = f2bf(vv >= 0.f ? vv : SLOPE * vv);
      }
    }
  }
}

// Direct message GEMM — T never materialized.
// msg[e,f] = sum_c A[e,c]*B[c,f], c = k*64+d, A[e,c] = u[e,k]*h[src_e,d]
// (A built in registers), B^T = w2e[f][c] (w2 + b2-as-bias-row, u_k=1).
// Block: 4 waves x 32 edges = 128 edges. B staged in LDS per 256-c chunk,
// each B-fragment shared by 2 M-tiles. Atomic scatter-add into agg.
__global__ __launch_bounds__(256) void k_msgd(
    const unsigned short* __restrict__ ubf, const unsigned short* __restrict__ hbf,
    const unsigned short* __restrict__ w2e, const int* __restrict__ ei,
    float* __restrict__ agg) {
  __shared__ unsigned short Bs[64 * LROW];
  int t = threadIdx.x;
  int w = t >> 6, lane = t & 63, lr = lane & 15, lg = lane >> 4;
  int ebase = (blockIdx.x * 4 + w) * 32;
  int e0 = ebase + lr, e1 = ebase + 16 + lr;
  int e0c = e0 < EE ? e0 : EE - 1;
  int e1c = e1 < EE ? e1 : EE - 1;
  int s0 = ei[e0c], s1 = ei[e1c];
  short8 hb0[2], hb1[2];     // h slices: [par] = h[s, par*32 + lg*8 .. +8]
  #pragma unroll
  for (int par = 0; par < 2; ++par) {
    hb0[par] = *(const short8*)(hbf + (size_t)s0 * DD + par * 32 + lg * 8);
    hb1[par] = *(const short8*)(hbf + (size_t)s1 * DD + par * 32 + lg * 8);
  }
  const unsigned short* u0 = ubf + (size_t)e0c * HH;
  const unsigned short* u1 = ubf + (size_t)e1c * HH;
  f32x4 acc[2][4] = {};
  for (int ch = 0; ch < NCH; ++ch) {
    // stage B chunk [64 f][256 c] -> LDS
    #pragma unroll
    for (int i = 0; i < 8; ++i) {
      int f = (t >> 4) + (i & 3) * 16;
      int o8 = (t & 15) + (i >> 2) * 16;
      short8 v = *(const short8*)(w2e + (size_t)f * BPAD + ch * 256 + o8 * 8);
      *(short8*)(&Bs[f * LROW + o8 * 8]) = v;
    }
    float uf0[4], uf1[4];
    if (ch < 32) {
      bf4 v0 = *(const bf4*)(u0 + ch * 4);
      bf4 v1 = *(const bf4*)(u1 + ch * 4);
      #pragma unroll
      for (int kk = 0; kk < 4; ++kk) {
        uf0[kk] = bf2f((unsigned short)v0[kk]);
        uf1[kk] = bf2f((unsigned short)v1[kk]);
      }
    } else {   // bias chunk: k' = 128 -> u = 1 (b2 rows), rest zero
      uf0[0] = 1.f; uf0[1] = 0.f; uf0[2] = 0.f; uf0[3] = 0.f;
      uf1[0] = 1.f; uf1[1] = 0.f; uf1[2] = 0.f; uf1[3] = 0.f;
    }
    __syncthreads();
    #pragma unroll
    for (int ks = 0; ks < 8; ++ks) {
      int par = ks & 1;
      float u0k = (ks >> 1) == 0 ? uf0[0] : (ks >> 1) == 1 ? uf0[1]
                 : (ks >> 1) == 2 ? uf0[2] : uf0[3];
      float u1k = (ks >> 1) == 0 ? uf1[0] : (ks >> 1) == 1 ? uf1[1]
                 : (ks >> 1) == 2 ? uf1[2] : uf1[3];
      union { unsigned u[4]; short8 s; } pk0, pk1;
      #pragma unroll
      for (int jj = 0; jj < 4; ++jj) {
        float pa = u0k * bf2f((unsigned short)hb0[par][jj * 2]);
        float pb = u0k * bf2f((unsigned short)hb0[par][jj * 2 + 1]);
        pk0.u[jj] = cvtpk(pa, pb);
        float qa = u1k * bf2f((unsigned short)hb1[par][jj * 2]);
        float qb = u1k * bf2f((unsigned short)hb1[par][jj * 2 + 1]);
        pk1.u[jj] = cvtpk(qa, qb);
      }
      int cb = ks * 32 + lg * 8;
      #pragma unroll
      for (int ft = 0; ft < 4; ++ft) {
        short8 b = *(const short8*)(&Bs[(ft * 16 + lr) * LROW + cb]);
        acc[0][ft] = __builtin_amdgcn_mfma_f32_16x16x32_bf16(pk0.s, b,
                                                             acc[0][ft], 0, 0, 0);
        acc[1][ft] = __builtin_amdgcn_mfma_f32_16x16x32_bf16(pk1.s, b,
                                                             acc[1][ft], 0, 0, 0);
      }
    }
    __syncthreads();
  }
  #pragma unroll
  for (int m = 0; m < 2; ++m)
    #pragma unroll
    for (int reg = 0; reg < 4; ++reg) {
      int ee = ebase + m * 16 + lg * 4 + reg;
      if (ee < EE) {
        int dstn = ei[EE + ee];
        #pragma unroll
        for (int ft = 0; ft < 4; ++ft)
          atomicAdd(&agg[(size_t)dstn * DD + ft * 16 + lr],
                    m == 0 ? acc[0][ft][reg] : acc[1][ft][reg]);
      }
    }
}

// out = x + agg/max(cnt,1) + h@root + bias
__global__ __launch_bounds__(256) void k_final(const float* __restrict__ x,
    const float* __restrict__ h, const float* __restrict__ root,
    const float* __restrict__ bias, const float* __restrict__ agg,
    const int* __restrict__ cnt, float* __restrict__ out) {
  __shared__ float Bs[DD][DD + 1];
  __shared__ float As[32][DD];
  int t = threadIdx.x;
  #pragma unroll
  for (int i = 0; i < 16; ++i) {
    int idx = t + i * 256;
    Bs[idx >> 6][idx & 63] = root[idx];
  }
  int row0 = blockIdx.x * 32;
  #pragma unroll
  for (int i = 0; i < 8; ++i) {
    int idx = t + i * 256;
    int r = idx >> 6, d = idx & 63;
    int gr = row0 + r;
    As[r][d] = (gr < NS) ? h[gr * DD + d] : 0.f;
  }
  __syncthreads();
  int r = t >> 3;
  int c0 = (t & 7) * 8;
  int gr = row0 + r;
  if (gr >= NS) return;
  float acc[8] = {};
  for (int d = 0; d < DD; ++d) {
    float a = As[r][d];
    #pragma unroll
    for (int j = 0; j < 8; ++j) acc[j] += a * Bs[d][c0 + j];
  }
  float inv = 1.0f / fmaxf((float)cnt[gr], 1.0f);
  #pragma unroll
  for (int j = 0; j < 8; ++j) {
    size_t gi = (size_t)gr * DD + c0 + j;
    out[gi] = x[gi] + agg[gi] * inv + acc[j] + bias[c0 + j];
  }
}

extern "C" void kernel_launch(void* const* d_in, const int* in_sizes, int n_in,
                              void* d_out, int out_size, void* d_ws, size_t ws_size,
                              hipStream_t stream) {
  const float* x     = (const float*)d_in[0];
  const float* ea    = (const float*)d_in[1];
  const float* gamma = (const float*)d_in[2];
  const float* beta  = (const float*)d_in[3];
  const float* w1    = (const float*)d_in[4];
  const float* b1    = (const float*)d_in[5];
  const float* w2    = (const float*)d_in[6];
  const float* b2    = (const float*)d_in[7];
  const float* root  = (const float*)d_in[8];
  const float* bias  = (const float*)d_in[9];
  const int*   ei    = (const int*)d_in[10];
  float* out = (float*)d_out;

  char* p = (char*)d_ws;
  auto carve = [&](size_t bytes) {
    char* q = p;
    p += (bytes + 255) & ~(size_t)255;
    return q;
  };
  float* h            = (float*)carve(sizeof(float) * NS * DD);
  unsigned short* hbf = (unsigned short*)carve(sizeof(short) * NS * DD);
  unsigned short* w2e = (unsigned short*)carve(sizeof(short) * (size_t)DD * BPAD);
  unsigned short* ubf = (unsigned short*)carve(sizeof(short) * (size_t)EE * HH);
  // contiguous zero-region: agg | cntdst (memset BEFORE k_prep — r13 lesson)
  char* z0 = p;
  float* agg          = (float*)carve(sizeof(float) * NS * DD);
  int* cntdst         = (int*)carve(sizeof(int) * NS);
  size_t zlen = (size_t)(p - z0);

  (void)hipMemsetAsync(z0, 0, zlen, stream);
  k_prep<<<dim3(TBLK + 1 + PBLK + UB), dim3(256), 0, stream>>>(
      x, gamma, beta, h, hbf, ea, w2, w2e, w1, b1, ubf, b2, ei, cntdst);
  k_msgd<<<dim3((EE + 127) / 128), dim3(256), 0, stream>>>(
      ubf, hbf, w2e, ei, agg);
  k_final<<<dim3((NS + 31) / 32), dim3(256), 0, stream>>>(x, h, root, bias, agg,
                                                          cntdst, out);
}

// Round 20
// 125.763 us; speedup vs baseline: 1.3263x; 1.3263x over previous
//
#include <hip/hip_runtime.h>

#define NS 10000
#define DD 64
#define HH 128
#define EE 50000
#define SLOPE 0.01f
#define BPAD 8448      // B^T row length in c (33 chunks x 256; 8192 w2 + 64 b2 + 192 zero)
#define NCH 33

typedef __attribute__((ext_vector_type(8))) short short8;
typedef __attribute__((ext_vector_type(4))) short bf4;
typedef __attribute__((ext_vector_type(4))) float f32x4;

static __device__ __forceinline__ unsigned short f2bf(float f) {
  unsigned int u = __float_as_uint(f);
  u += 0x7fff + ((u >> 16) & 1);   // round-to-nearest-even
  return (unsigned short)(u >> 16);
}
static __device__ __forceinline__ float bf2f(unsigned short s) {
  return __uint_as_float((unsigned int)s << 16);
}
static __device__ __forceinline__ unsigned cvtpk(float lo, float hi) {
  unsigned r;
  asm("v_cvt_pk_bf16_f32 %0, %1, %2" : "=v"(r) : "v"(lo), "v"(hi));
  return r;
}

__device__ __forceinline__ float wave_sum64(float v) {
  #pragma unroll
  for (int m = 32; m >= 1; m >>= 1) v += __shfl_xor(v, m, 64);
  return v;
}

// k_prep: [0,128): w2 64x64 LDS transpose -> w2e rows (stride BPAD).
//         [128]: b2 rows + zero pad of w2e.
//         [129, 129+2500): LN -> h/hbf, cntdst.
//         [2629, 2629+782): u-GEMM (inline ea cast + w1 LDS transpose) -> ubf.
// agg|cntdst zeroed by a prior memset (r13 race lesson).
#define TBLK 128
#define PBLK 2500
#define UB 782
__global__ __launch_bounds__(256) void k_prep(const float* __restrict__ x,
    const float* __restrict__ gamma, const float* __restrict__ beta,
    float* __restrict__ h, unsigned short* __restrict__ hbf,
    const float* __restrict__ ea, const float* __restrict__ w2,
    unsigned short* __restrict__ w2e, const float* __restrict__ w1,
    const float* __restrict__ b1, unsigned short* __restrict__ ubf,
    const float* __restrict__ b2, const int* __restrict__ ei,
    int* __restrict__ cntdst) {
  __shared__ __align__(16) unsigned char smem[18432];
  int t = threadIdx.x;
  int bid = blockIdx.x;
  if (bid < TBLK) {
    float (*tile)[65] = (float(*)[65])smem;   // 16640 B
    int k = bid;
    #pragma unroll
    for (int i = 0; i < 16; ++i) {
      int idx = t + i * 256;          // d*64+f
      tile[idx >> 6][idx & 63] = w2[k * (DD * DD) + idx];
    }
    __syncthreads();
    #pragma unroll
    for (int it = 0; it < 2; ++it) {
      int slot = t + it * 256;        // 0..511
      int f = slot >> 3, l8 = slot & 7;
      short8 o;
      #pragma unroll
      for (int j = 0; j < 8; ++j) o[j] = f2bf(tile[l8 * 8 + j][f]);
      *(short8*)(w2e + (size_t)f * BPAD + k * DD + l8 * 8) = o;
    }
    return;
  }
  if (bid == TBLK) {
    // b2 rows: w2e[f][8192+d] = b2[d*64+f]
    #pragma unroll
    for (int i = 0; i < 16; ++i) {
      int idx = t + i * 256;          // d*64+f
      int d = idx >> 6, f = idx & 63;
      w2e[(size_t)f * BPAD + 8192 + d] = f2bf(b2[idx]);
    }
    // zero pad: c in [8256, 8448)
    #pragma unroll
    for (int i = 0; i < 6; ++i) {
      int slot = t + i * 256;         // 0..1535
      int f = slot / 24, z8 = slot % 24;
      short8 z = {};
      *(short8*)(w2e + (size_t)f * BPAD + 8256 + z8 * 8) = z;
    }
    return;
  }
  if (bid < TBLK + 1 + PBLK) {
    int pbid = bid - TBLK - 1;
    int gid = pbid * 256 + t;
    if (gid < EE) atomicAdd(&cntdst[ei[EE + gid]], 1);
    int wid = t >> 6;
    int lane = t & 63;
    int row = pbid * 4 + wid;
    if (row >= NS) return;
    float v = x[row * DD + lane];
    float s = wave_sum64(v);
    float s2 = wave_sum64(v * v);
    float mu = s * (1.0f / 64.0f);
    float var = s2 * (1.0f / 64.0f) - mu * mu;
    float r = rsqrtf(var + 1e-5f);
    float hn = (v - mu) * r * gamma[lane] + beta[lane];
    float hv = hn >= 0.f ? hn : SLOPE * hn;
    h[row * DD + lane] = hv;
    hbf[row * DD + lane] = f2bf(hv);
    return;
  }
  // u-GEMM: 64 edge-rows per block, inline ea cast, w1 via LDS transpose.
  int ublk = bid - TBLK - 1 - PBLK;
  unsigned short (*W)[72] = (unsigned short(*)[72])smem;   // 128x72 shorts
  int w = t >> 6, lane = t & 63, lr = lane & 15, lg = lane >> 4;
  int r0 = ublk * 64 + w * 16;
  int ra = r0 + lr; if (ra >= EE) ra = EE - 1;
  const float* ep = ea + (size_t)ra * DD;
  float4 e0 = *(const float4*)(ep + lg * 8);
  float4 e1 = *(const float4*)(ep + lg * 8 + 4);
  float4 e2 = *(const float4*)(ep + 32 + lg * 8);
  float4 e3 = *(const float4*)(ep + 32 + lg * 8 + 4);
  #pragma unroll
  for (int i = 0; i < 32; ++i) {
    int idx = t + i * 256;            // idx = d*128 + hc
    int d = idx >> 7, hc = idx & 127;
    W[hc][d] = f2bf(w1[idx]);
  }
  __syncthreads();
  short8 a0, a1;
  a0[0] = f2bf(e0.x); a0[1] = f2bf(e0.y); a0[2] = f2bf(e0.z); a0[3] = f2bf(e0.w);
  a0[4] = f2bf(e1.x); a0[5] = f2bf(e1.y); a0[6] = f2bf(e1.z); a0[7] = f2bf(e1.w);
  a1[0] = f2bf(e2.x); a1[1] = f2bf(e2.y); a1[2] = f2bf(e2.z); a1[3] = f2bf(e2.w);
  a1[4] = f2bf(e3.x); a1[5] = f2bf(e3.y); a1[6] = f2bf(e3.z); a1[7] = f2bf(e3.w);
  short8 bb0[8], bb1[8];
  #pragma unroll
  for (int ni = 0; ni < 8; ++ni) {
    bb0[ni] = *(const short8*)(&W[ni * 16 + lr][lg * 8]);
    bb1[ni] = *(const short8*)(&W[ni * 16 + lr][32 + lg * 8]);
  }
  f32x4 acc[8] = {};
  #pragma unroll
  for (int ni = 0; ni < 8; ++ni) {
    acc[ni] = __builtin_amdgcn_mfma_f32_16x16x32_bf16(a0, bb0[ni], acc[ni], 0, 0, 0);
    acc[ni] = __builtin_amdgcn_mfma_f32_16x16x32_bf16(a1, bb1[ni], acc[ni], 0, 0, 0);
  }
  #pragma unroll
  for (int ni = 0; ni < 8; ++ni) {
    int col = ni * 16 + lr;
    float bb = b1[col];
    #pragma unroll
    for (int reg = 0; reg < 4; ++reg) {
      int gr = r0 + lg * 4 + reg;
      if (gr < EE) {
        float vv = acc[ni][reg] + bb;
        ubf[(size_t)gr * HH + col] = f2bf(vv >= 0.f ? vv : SLOPE * vv);
      }
    }
  }
}

// Direct message GEMM, c-split 4-way (blockIdx.y), XOR-swizzled B tile.
// msg[e,f] = sum_c A[e,c]*B[c,f]; A[e,c]=u[e,k]*h[src,d] built in registers.
// Block: 4 waves x 32 edges; y-block owns 8 c-chunks (y==3 adds bias chunk).
// Partial-c sums combine via the atomic scatter-add (linearity).
__global__ __launch_bounds__(256) void k_msgd(
    const unsigned short* __restrict__ ubf, const unsigned short* __restrict__ hbf,
    const unsigned short* __restrict__ w2e, const int* __restrict__ ei,
    float* __restrict__ agg) {
  __shared__ unsigned short Bs[64 * 256];   // 32 KB, swizzled o8 ^= (f&7)
  int t = threadIdx.x;
  int w = t >> 6, lane = t & 63, lr = lane & 15, lg = lane >> 4;
  int cq = blockIdx.y;
  int nch = (cq == 3) ? 9 : 8;
  int ebase = (blockIdx.x * 4 + w) * 32;
  int e0 = ebase + lr, e1 = ebase + 16 + lr;
  int e0c = e0 < EE ? e0 : EE - 1;
  int e1c = e1 < EE ? e1 : EE - 1;
  int s0 = ei[e0c], s1 = ei[e1c];
  short8 hb0[2], hb1[2];     // h slices: [par] = h[s, par*32 + lg*8 .. +8]
  #pragma unroll
  for (int par = 0; par < 2; ++par) {
    hb0[par] = *(const short8*)(hbf + (size_t)s0 * DD + par * 32 + lg * 8);
    hb1[par] = *(const short8*)(hbf + (size_t)s1 * DD + par * 32 + lg * 8);
  }
  const unsigned short* u0 = ubf + (size_t)e0c * HH;
  const unsigned short* u1 = ubf + (size_t)e1c * HH;
  f32x4 acc[2][4] = {};
  for (int ci = 0; ci < nch; ++ci) {
    int ch = (ci < 8) ? (cq * 8 + ci) : 32;
    // stage B chunk [64 f][256 c] -> LDS, swizzled: slot o8 ^ (f&7)
    #pragma unroll
    for (int i = 0; i < 8; ++i) {
      int f = (t >> 4) + (i & 3) * 16;
      int o8 = (t & 15) + (i >> 2) * 16;
      short8 v = *(const short8*)(w2e + (size_t)f * BPAD + ch * 256 + o8 * 8);
      *(short8*)(&Bs[f * 256 + (o8 ^ (f & 7)) * 8]) = v;
    }
    float uf0[4], uf1[4];
    if (ch < 32) {
      bf4 v0 = *(const bf4*)(u0 + ch * 4);
      bf4 v1 = *(const bf4*)(u1 + ch * 4);
      #pragma unroll
      for (int kk = 0; kk < 4; ++kk) {
        uf0[kk] = bf2f((unsigned short)v0[kk]);
        uf1[kk] = bf2f((unsigned short)v1[kk]);
      }
    } else {   // bias chunk: k' = 128 -> u = 1 (b2 rows), rest zero
      uf0[0] = 1.f; uf0[1] = 0.f; uf0[2] = 0.f; uf0[3] = 0.f;
      uf1[0] = 1.f; uf1[1] = 0.f; uf1[2] = 0.f; uf1[3] = 0.f;
    }
    __syncthreads();
    #pragma unroll
    for (int ks = 0; ks < 8; ++ks) {
      int par = ks & 1;
      float u0k = (ks >> 1) == 0 ? uf0[0] : (ks >> 1) == 1 ? uf0[1]
                 : (ks >> 1) == 2 ? uf0[2] : uf0[3];
      float u1k = (ks >> 1) == 0 ? uf1[0] : (ks >> 1) == 1 ? uf1[1]
                 : (ks >> 1) == 2 ? uf1[2] : uf1[3];
      union { unsigned u[4]; short8 s; } pk0, pk1;
      #pragma unroll
      for (int jj = 0; jj < 4; ++jj) {
        float pa = u0k * bf2f((unsigned short)hb0[par][jj * 2]);
        float pb = u0k * bf2f((unsigned short)hb0[par][jj * 2 + 1]);
        pk0.u[jj] = cvtpk(pa, pb);
        float qa = u1k * bf2f((unsigned short)hb1[par][jj * 2]);
        float qb = u1k * bf2f((unsigned short)hb1[par][jj * 2 + 1]);
        pk1.u[jj] = cvtpk(qa, qb);
      }
      int o8r = ks * 4 + lg;
      #pragma unroll
      for (int ft = 0; ft < 4; ++ft) {
        int f = ft * 16 + lr;
        short8 b = *(const short8*)(&Bs[f * 256 + (o8r ^ (f & 7)) * 8]);
        acc[0][ft] = __builtin_amdgcn_mfma_f32_16x16x32_bf16(pk0.s, b,
                                                             acc[0][ft], 0, 0, 0);
        acc[1][ft] = __builtin_amdgcn_mfma_f32_16x16x32_bf16(pk1.s, b,
                                                             acc[1][ft], 0, 0, 0);
      }
    }
    __syncthreads();
  }
  #pragma unroll
  for (int m = 0; m < 2; ++m)
    #pragma unroll
    for (int reg = 0; reg < 4; ++reg) {
      int ee = ebase + m * 16 + lg * 4 + reg;
      if (ee < EE) {
        int dstn = ei[EE + ee];
        #pragma unroll
        for (int ft = 0; ft < 4; ++ft)
          atomicAdd(&agg[(size_t)dstn * DD + ft * 16 + lr],
                    m == 0 ? acc[0][ft][reg] : acc[1][ft][reg]);
      }
    }
}

// out = x + agg/max(cnt,1) + h@root + bias
__global__ __launch_bounds__(256) void k_final(const float* __restrict__ x,
    const float* __restrict__ h, const float* __restrict__ root,
    const float* __restrict__ bias, const float* __restrict__ agg,
    const int* __restrict__ cnt, float* __restrict__ out) {
  __shared__ float Bs[DD][DD + 1];
  __shared__ float As[32][DD];
  int t = threadIdx.x;
  #pragma unroll
  for (int i = 0; i < 16; ++i) {
    int idx = t + i * 256;
    Bs[idx >> 6][idx & 63] = root[idx];
  }
  int row0 = blockIdx.x * 32;
  #pragma unroll
  for (int i = 0; i < 8; ++i) {
    int idx = t + i * 256;
    int r = idx >> 6, d = idx & 63;
    int gr = row0 + r;
    As[r][d] = (gr < NS) ? h[gr * DD + d] : 0.f;
  }
  __syncthreads();
  int r = t >> 3;
  int c0 = (t & 7) * 8;
  int gr = row0 + r;
  if (gr >= NS) return;
  float acc[8] = {};
  for (int d = 0; d < DD; ++d) {
    float a = As[r][d];
    #pragma unroll
    for (int j = 0; j < 8; ++j) acc[j] += a * Bs[d][c0 + j];
  }
  float inv = 1.0f / fmaxf((float)cnt[gr], 1.0f);
  #pragma unroll
  for (int j = 0; j < 8; ++j) {
    size_t gi = (size_t)gr * DD + c0 + j;
    out[gi] = x[gi] + agg[gi] * inv + acc[j] + bias[c0 + j];
  }
}

extern "C" void kernel_launch(void* const* d_in, const int* in_sizes, int n_in,
                              void* d_out, int out_size, void* d_ws, size_t ws_size,
                              hipStream_t stream) {
  const float* x     = (const float*)d_in[0];
  const float* ea    = (const float*)d_in[1];
  const float* gamma = (const float*)d_in[2];
  const float* beta  = (const float*)d_in[3];
  const float* w1    = (const float*)d_in[4];
  const float* b1    = (const float*)d_in[5];
  const float* w2    = (const float*)d_in[6];
  const float* b2    = (const float*)d_in[7];
  const float* root  = (const float*)d_in[8];
  const float* bias  = (const float*)d_in[9];
  const int*   ei    = (const int*)d_in[10];
  float* out = (float*)d_out;

  char* p = (char*)d_ws;
  auto carve = [&](size_t bytes) {
    char* q = p;
    p += (bytes + 255) & ~(size_t)255;
    return q;
  };
  float* h            = (float*)carve(sizeof(float) * NS * DD);
  unsigned short* hbf = (unsigned short*)carve(sizeof(short) * NS * DD);
  unsigned short* w2e = (unsigned short*)carve(sizeof(short) * (size_t)DD * BPAD);
  unsigned short* ubf = (unsigned short*)carve(sizeof(short) * (size_t)EE * HH);
  // contiguous zero-region: agg | cntdst (memset BEFORE k_prep — r13 lesson)
  char* z0 = p;
  float* agg          = (float*)carve(sizeof(float) * NS * DD);
  int* cntdst         = (int*)carve(sizeof(int) * NS);
  size_t zlen = (size_t)(p - z0);

  (void)hipMemsetAsync(z0, 0, zlen, stream);
  k_prep<<<dim3(TBLK + 1 + PBLK + UB), dim3(256), 0, stream>>>(
      x, gamma, beta, h, hbf, ea, w2, w2e, w1, b1, ubf, b2, ei, cntdst);
  k_msgd<<<dim3((EE + 127) / 128, 4), dim3(256), 0, stream>>>(
      ubf, hbf, w2e, ei, agg);
  k_final<<<dim3((NS + 31) / 32), dim3(256), 0, stream>>>(x, h, root, bias, agg,
                                                          cntdst, out);
}

// Round 21
// 122.257 us; speedup vs baseline: 1.3643x; 1.0287x over previous
//
#include <hip/hip_runtime.h>

#define NS 10000
#define DD 64
#define HH 128
#define EE 50000
#define SLOPE 0.01f
#define BPAD 8448      // B^T row length in c (33 chunks x 256; 8192 w2 + 64 b2 + 192 zero)
#define NCH 33

typedef __attribute__((ext_vector_type(8))) short short8;
typedef __attribute__((ext_vector_type(4))) short bf4;
typedef __attribute__((ext_vector_type(4))) float f32x4;

static __device__ __forceinline__ unsigned short f2bf(float f) {
  unsigned int u = __float_as_uint(f);
  u += 0x7fff + ((u >> 16) & 1);   // round-to-nearest-even
  return (unsigned short)(u >> 16);
}
static __device__ __forceinline__ float bf2f(unsigned short s) {
  return __uint_as_float((unsigned int)s << 16);
}
static __device__ __forceinline__ unsigned cvtpk(float lo, float hi) {
  unsigned r;
  asm("v_cvt_pk_bf16_f32 %0, %1, %2" : "=v"(r) : "v"(lo), "v"(hi));
  return r;
}

__device__ __forceinline__ float wave_sum64(float v) {
  #pragma unroll
  for (int m = 32; m >= 1; m >>= 1) v += __shfl_xor(v, m, 64);
  return v;
}

// k_prep: [0,128): w2 64x64 LDS transpose -> w2e rows (stride BPAD).
//         [128]: b2 rows + zero pad of w2e.
//         [129, 129+2500): LN -> h/hbf, cntdst.
//         [2629, 2629+782): u-GEMM (inline ea cast + w1 LDS transpose) -> ubf.
// agg|cntdst zeroed by a prior memset (r13 race lesson).
#define TBLK 128
#define PBLK 2500
#define UB 782
__global__ __launch_bounds__(256) void k_prep(const float* __restrict__ x,
    const float* __restrict__ gamma, const float* __restrict__ beta,
    float* __restrict__ h, unsigned short* __restrict__ hbf,
    const float* __restrict__ ea, const float* __restrict__ w2,
    unsigned short* __restrict__ w2e, const float* __restrict__ w1,
    const float* __restrict__ b1, unsigned short* __restrict__ ubf,
    const float* __restrict__ b2, const int* __restrict__ ei,
    int* __restrict__ cntdst) {
  __shared__ __align__(16) unsigned char smem[18432];
  int t = threadIdx.x;
  int bid = blockIdx.x;
  if (bid < TBLK) {
    float (*tile)[65] = (float(*)[65])smem;   // 16640 B
    int k = bid;
    #pragma unroll
    for (int i = 0; i < 16; ++i) {
      int idx = t + i * 256;          // d*64+f
      tile[idx >> 6][idx & 63] = w2[k * (DD * DD) + idx];
    }
    __syncthreads();
    #pragma unroll
    for (int it = 0; it < 2; ++it) {
      int slot = t + it * 256;        // 0..511
      int f = slot >> 3, l8 = slot & 7;
      short8 o;
      #pragma unroll
      for (int j = 0; j < 8; ++j) o[j] = f2bf(tile[l8 * 8 + j][f]);
      *(short8*)(w2e + (size_t)f * BPAD + k * DD + l8 * 8) = o;
    }
    return;
  }
  if (bid == TBLK) {
    // b2 rows: w2e[f][8192+d] = b2[d*64+f]
    #pragma unroll
    for (int i = 0; i < 16; ++i) {
      int idx = t + i * 256;          // d*64+f
      int d = idx >> 6, f = idx & 63;
      w2e[(size_t)f * BPAD + 8192 + d] = f2bf(b2[idx]);
    }
    // zero pad: c in [8256, 8448)
    #pragma unroll
    for (int i = 0; i < 6; ++i) {
      int slot = t + i * 256;         // 0..1535
      int f = slot / 24, z8 = slot % 24;
      short8 z = {};
      *(short8*)(w2e + (size_t)f * BPAD + 8256 + z8 * 8) = z;
    }
    return;
  }
  if (bid < TBLK + 1 + PBLK) {
    int pbid = bid - TBLK - 1;
    int gid = pbid * 256 + t;
    if (gid < EE) atomicAdd(&cntdst[ei[EE + gid]], 1);
    int wid = t >> 6;
    int lane = t & 63;
    int row = pbid * 4 + wid;
    if (row >= NS) return;
    float v = x[row * DD + lane];
    float s = wave_sum64(v);
    float s2 = wave_sum64(v * v);
    float mu = s * (1.0f / 64.0f);
    float var = s2 * (1.0f / 64.0f) - mu * mu;
    float r = rsqrtf(var + 1e-5f);
    float hn = (v - mu) * r * gamma[lane] + beta[lane];
    float hv = hn >= 0.f ? hn : SLOPE * hn;
    h[row * DD + lane] = hv;
    hbf[row * DD + lane] = f2bf(hv);
    return;
  }
  // u-GEMM: 64 edge-rows per block, inline ea cast, w1 via LDS transpose.
  int ublk = bid - TBLK - 1 - PBLK;
  unsigned short (*W)[72] = (unsigned short(*)[72])smem;   // 128x72 shorts
  int w = t >> 6, lane = t & 63, lr = lane & 15, lg = lane >> 4;
  int r0 = ublk * 64 + w * 16;
  int ra = r0 + lr; if (ra >= EE) ra = EE - 1;
  const float* ep = ea + (size_t)ra * DD;
  float4 e0 = *(const float4*)(ep + lg * 8);
  float4 e1 = *(const float4*)(ep + lg * 8 + 4);
  float4 e2 = *(const float4*)(ep + 32 + lg * 8);
  float4 e3 = *(const float4*)(ep + 32 + lg * 8 + 4);
  #pragma unroll
  for (int i = 0; i < 32; ++i) {
    int idx = t + i * 256;            // idx = d*128 + hc
    int d = idx >> 7, hc = idx & 127;
    W[hc][d] = f2bf(w1[idx]);
  }
  __syncthreads();
  short8 a0, a1;
  a0[0] = f2bf(e0.x); a0[1] = f2bf(e0.y); a0[2] = f2bf(e0.z); a0[3] = f2bf(e0.w);
  a0[4] = f2bf(e1.x); a0[5] = f2bf(e1.y); a0[6] = f2bf(e1.z); a0[7] = f2bf(e1.w);
  a1[0] = f2bf(e2.x); a1[1] = f2bf(e2.y); a1[2] = f2bf(e2.z); a1[3] = f2bf(e2.w);
  a1[4] = f2bf(e3.x); a1[5] = f2bf(e3.y); a1[6] = f2bf(e3.z); a1[7] = f2bf(e3.w);
  short8 bb0[8], bb1[8];
  #pragma unroll
  for (int ni = 0; ni < 8; ++ni) {
    bb0[ni] = *(const short8*)(&W[ni * 16 + lr][lg * 8]);
    bb1[ni] = *(const short8*)(&W[ni * 16 + lr][32 + lg * 8]);
  }
  f32x4 acc[8] = {};
  #pragma unroll
  for (int ni = 0; ni < 8; ++ni) {
    acc[ni] = __builtin_amdgcn_mfma_f32_16x16x32_bf16(a0, bb0[ni], acc[ni], 0, 0, 0);
    acc[ni] = __builtin_amdgcn_mfma_f32_16x16x32_bf16(a1, bb1[ni], acc[ni], 0, 0, 0);
  }
  #pragma unroll
  for (int ni = 0; ni < 8; ++ni) {
    int col = ni * 16 + lr;
    float bb = b1[col];
    #pragma unroll
    for (int reg = 0; reg < 4; ++reg) {
      int gr = r0 + lg * 4 + reg;
      if (gr < EE) {
        float vv = acc[ni][reg] + bb;
        ubf[(size_t)gr * HH + col] = f2bf(vv >= 0.f ? vv : SLOPE * vv);
      }
    }
  }
}

// Direct message GEMM, c-split 4-way, f32-h A-build (no bf2f shifts),
// T14 async staging (prefetch next B chunk into regs during compute).
__global__ __launch_bounds__(256) void k_msgd(
    const unsigned short* __restrict__ ubf, const float* __restrict__ hf,
    const unsigned short* __restrict__ w2e, const int* __restrict__ ei,
    float* __restrict__ agg) {
  __shared__ unsigned short Bs[64 * 256];   // 32 KB
  int t = threadIdx.x;
  int w = t >> 6, lane = t & 63, lr = lane & 15, lg = lane >> 4;
  int cq = blockIdx.y;
  int nch = (cq == 3) ? 9 : 8;
  int ebase = (blockIdx.x * 4 + w) * 32;
  int e0 = ebase + lr, e1 = ebase + 16 + lr;
  int e0c = e0 < EE ? e0 : EE - 1;
  int e1c = e1 < EE ? e1 : EE - 1;
  int s0 = ei[e0c], s1 = ei[e1c];
  // h slices in f32: [par][j] = h[s, par*32 + lg*8 + j]
  float h0[2][8], h1[2][8];
  #pragma unroll
  for (int par = 0; par < 2; ++par) {
    const float* p0 = hf + (size_t)s0 * DD + par * 32 + lg * 8;
    const float* p1 = hf + (size_t)s1 * DD + par * 32 + lg * 8;
    *(float4*)(&h0[par][0]) = *(const float4*)(p0);
    *(float4*)(&h0[par][4]) = *(const float4*)(p0 + 4);
    *(float4*)(&h1[par][0]) = *(const float4*)(p1);
    *(float4*)(&h1[par][4]) = *(const float4*)(p1 + 4);
  }
  const unsigned short* u0 = ubf + (size_t)e0c * HH;
  const unsigned short* u1 = ubf + (size_t)e1c * HH;
  // stage-reg prefetch of first chunk
  int sf = (t >> 4);          // base f (0..15), +16*(i&3)
  int so8 = (t & 15);         // base o8 (0..15), +16*(i>>2)
  short8 sreg[8];
  {
    int ch0 = cq * 8;
    #pragma unroll
    for (int i = 0; i < 8; ++i) {
      int f = sf + (i & 3) * 16;
      int o8 = so8 + (i >> 2) * 16;
      sreg[i] = *(const short8*)(w2e + (size_t)f * BPAD + ch0 * 256 + o8 * 8);
    }
  }
  f32x4 acc[2][4] = {};
  for (int ci = 0; ci < nch; ++ci) {
    int ch = (ci < 8) ? (cq * 8 + ci) : 32;
    __syncthreads();            // prev compute done; LDS free
    #pragma unroll
    for (int i = 0; i < 8; ++i) {
      int f = sf + (i & 3) * 16;
      int o8 = so8 + (i >> 2) * 16;
      *(short8*)(&Bs[f * 256 + (o8 ^ (f & 7)) * 8]) = sreg[i];
    }
    if (ci + 1 < nch) {         // T14: issue next-chunk loads now
      int ch2 = (ci + 1 < 8) ? (cq * 8 + ci + 1) : 32;
      #pragma unroll
      for (int i = 0; i < 8; ++i) {
        int f = sf + (i & 3) * 16;
        int o8 = so8 + (i >> 2) * 16;
        sreg[i] = *(const short8*)(w2e + (size_t)f * BPAD + ch2 * 256 + o8 * 8);
      }
    }
    float uf0[4], uf1[4];
    if (ch < 32) {
      bf4 v0 = *(const bf4*)(u0 + ch * 4);
      bf4 v1 = *(const bf4*)(u1 + ch * 4);
      #pragma unroll
      for (int kk = 0; kk < 4; ++kk) {
        uf0[kk] = bf2f((unsigned short)v0[kk]);
        uf1[kk] = bf2f((unsigned short)v1[kk]);
      }
    } else {   // bias chunk: k' = 0 -> u = 1 (b2 rows), rest zero
      uf0[0] = 1.f; uf0[1] = 0.f; uf0[2] = 0.f; uf0[3] = 0.f;
      uf1[0] = 1.f; uf1[1] = 0.f; uf1[2] = 0.f; uf1[3] = 0.f;
    }
    __syncthreads();            // Bs ready
    #pragma unroll
    for (int ks = 0; ks < 8; ++ks) {
      int par = ks & 1;
      float u0k = (ks >> 1) == 0 ? uf0[0] : (ks >> 1) == 1 ? uf0[1]
                 : (ks >> 1) == 2 ? uf0[2] : uf0[3];
      float u1k = (ks >> 1) == 0 ? uf1[0] : (ks >> 1) == 1 ? uf1[1]
                 : (ks >> 1) == 2 ? uf1[2] : uf1[3];
      union { unsigned u[4]; short8 s; } pk0, pk1;
      #pragma unroll
      for (int jj = 0; jj < 4; ++jj) {
        pk0.u[jj] = cvtpk(u0k * h0[par][jj * 2], u0k * h0[par][jj * 2 + 1]);
        pk1.u[jj] = cvtpk(u1k * h1[par][jj * 2], u1k * h1[par][jj * 2 + 1]);
      }
      int o8r = ks * 4 + lg;
      #pragma unroll
      for (int ft = 0; ft < 4; ++ft) {
        int f = ft * 16 + lr;
        short8 b = *(const short8*)(&Bs[f * 256 + (o8r ^ (f & 7)) * 8]);
        acc[0][ft] = __builtin_amdgcn_mfma_f32_16x16x32_bf16(pk0.s, b,
                                                             acc[0][ft], 0, 0, 0);
        acc[1][ft] = __builtin_amdgcn_mfma_f32_16x16x32_bf16(pk1.s, b,
                                                             acc[1][ft], 0, 0, 0);
      }
    }
  }
  #pragma unroll
  for (int m = 0; m < 2; ++m)
    #pragma unroll
    for (int reg = 0; reg < 4; ++reg) {
      int ee = ebase + m * 16 + lg * 4 + reg;
      if (ee < EE) {
        int dstn = ei[EE + ee];
        #pragma unroll
        for (int ft = 0; ft < 4; ++ft)
          atomicAdd(&agg[(size_t)dstn * DD + ft * 16 + lr],
                    m == 0 ? acc[0][ft][reg] : acc[1][ft][reg]);
      }
    }
}

// out = x + agg/max(cnt,1) + h@root + bias
__global__ __launch_bounds__(256) void k_final(const float* __restrict__ x,
    const float* __restrict__ h, const float* __restrict__ root,
    const float* __restrict__ bias, const float* __restrict__ agg,
    const int* __restrict__ cnt, float* __restrict__ out) {
  __shared__ float Bs[DD][DD + 1];
  __shared__ float As[32][DD];
  int t = threadIdx.x;
  #pragma unroll
  for (int i = 0; i < 16; ++i) {
    int idx = t + i * 256;
    Bs[idx >> 6][idx & 63] = root[idx];
  }
  int row0 = blockIdx.x * 32;
  #pragma unroll
  for (int i = 0; i < 8; ++i) {
    int idx = t + i * 256;
    int r = idx >> 6, d = idx & 63;
    int gr = row0 + r;
    As[r][d] = (gr < NS) ? h[gr * DD + d] : 0.f;
  }
  __syncthreads();
  int r = t >> 3;
  int c0 = (t & 7) * 8;
  int gr = row0 + r;
  if (gr >= NS) return;
  float acc[8] = {};
  for (int d = 0; d < DD; ++d) {
    float a = As[r][d];
    #pragma unroll
    for (int j = 0; j < 8; ++j) acc[j] += a * Bs[d][c0 + j];
  }
  float inv = 1.0f / fmaxf((float)cnt[gr], 1.0f);
  #pragma unroll
  for (int j = 0; j < 8; ++j) {
    size_t gi = (size_t)gr * DD + c0 + j;
    out[gi] = x[gi] + agg[gi] * inv + acc[j] + bias[c0 + j];
  }
}

extern "C" void kernel_launch(void* const* d_in, const int* in_sizes, int n_in,
                              void* d_out, int out_size, void* d_ws, size_t ws_size,
                              hipStream_t stream) {
  const float* x     = (const float*)d_in[0];
  const float* ea    = (const float*)d_in[1];
  const float* gamma = (const float*)d_in[2];
  const float* beta  = (const float*)d_in[3];
  const float* w1    = (const float*)d_in[4];
  const float* b1    = (const float*)d_in[5];
  const float* w2    = (const float*)d_in[6];
  const float* b2    = (const float*)d_in[7];
  const float* root  = (const float*)d_in[8];
  const float* bias  = (const float*)d_in[9];
  const int*   ei    = (const int*)d_in[10];
  float* out = (float*)d_out;

  char* p = (char*)d_ws;
  auto carve = [&](size_t bytes) {
    char* q = p;
    p += (bytes + 255) & ~(size_t)255;
    return q;
  };
  float* h            = (float*)carve(sizeof(float) * NS * DD);
  unsigned short* hbf = (unsigned short*)carve(sizeof(short) * NS * DD);
  unsigned short* w2e = (unsigned short*)carve(sizeof(short) * (size_t)DD * BPAD);
  unsigned short* ubf = (unsigned short*)carve(sizeof(short) * (size_t)EE * HH);
  // contiguous zero-region: agg | cntdst (memset BEFORE k_prep — r13 lesson)
  char* z0 = p;
  float* agg          = (float*)carve(sizeof(float) * NS * DD);
  int* cntdst         = (int*)carve(sizeof(int) * NS);
  size_t zlen = (size_t)(p - z0);

  (void)hipMemsetAsync(z0, 0, zlen, stream);
  k_prep<<<dim3(TBLK + 1 + PBLK + UB), dim3(256), 0, stream>>>(
      x, gamma, beta, h, hbf, ea, w2, w2e, w1, b1, ubf, b2, ei, cntdst);
  k_msgd<<<dim3((EE + 127) / 128, 4), dim3(256), 0, stream>>>(
      ubf, h, w2e, ei, agg);
  k_final<<<dim3((NS + 31) / 32), dim3(256), 0, stream>>>(x, h, root, bias, agg,
                                                          cntdst, out);
}